// Round 14
// baseline (76.933 us; speedup 1.0000x reference)
//
#include <hip/hip_runtime.h>
#include <math.h>

#define NB 2
#define QN 8192
#define DIM 256
#define S_TOT 5440   // 4096+1024+256+64

typedef unsigned int uint32;
typedef _Float16 f16;
typedef __attribute__((ext_vector_type(8))) _Float16 h8;   // MFMA A/B frag (4 VGPR)
typedef __attribute__((ext_vector_type(4))) _Float16 h4;
typedef __attribute__((ext_vector_type(2))) _Float16 h2;
typedef __attribute__((ext_vector_type(4))) float f32x4;   // MFMA C/D frag

__device__ __forceinline__ int pack_h2(float w) {
  union { h2 h; int i; } u; const f16 wh = (f16)w; u.h = h2{wh, wh};
  return u.i;
}
__device__ __forceinline__ int bucket_of(const float* refp, int q) {
  const float rx = refp[(size_t)q * 2], ry = refp[(size_t)q * 2 + 1];
  const int bx = min(15, max(0, (int)(rx * 16.f)));
  const int by = min(15, max(0, (int)(ry * 16.f)));
  return ((q >> 13) << 8) | (by << 4) | bx;
}

// Fragment-linear layout: element (row s, col k) of a [S][256] f16 matrix lives
// at  ((s>>4)*32 + (k>>3))*128 + (s&15)*8 + (k&7).

// ---------------------------------------------------------------------------
// prep: query->qf frag f16; feat->featT_f; weights->W*_f; zero hist/cnt.
// grid.x: [0,128) query, [128,468) feat, [468,496) weights, 496 zero.
// ---------------------------------------------------------------------------
__global__ __launch_bounds__(256) void prep_kernel(
    const float* __restrict__ q,
    const float* __restrict__ f0, const float* __restrict__ f1,
    const float* __restrict__ f2, const float* __restrict__ f3,
    const float* __restrict__ W_off, const float* __restrict__ W_attn,
    const float* __restrict__ W_val, const float* __restrict__ W_out,
    f16* __restrict__ qf, f16* __restrict__ featT_f,
    f16* __restrict__ Wcat_f, f16* __restrict__ Wval_f, f16* __restrict__ Wout_f,
    int* __restrict__ hist, int* __restrict__ cnt) {
  const int t = blockIdx.x, y = blockIdx.y, tid = threadIdx.x;

  if (t == 496) {  // zero hist + cnt (runs 8x via y; benign)
    hist[tid] = 0; hist[tid + 256] = 0;
    cnt[tid] = 0;  cnt[tid + 256] = 0;
    return;
  }

  if (t < 128) {
    const int row0 = (t * 8 + y) * 16;
    const int s_l = tid >> 4, c8 = tid & 15;
    const float* src = q + (size_t)(row0 + s_l) * 256;
#pragma unroll
    for (int cc = 0; cc < 2; ++cc) {
      const int c8c = c8 + cc * 16;
      const float4 u0 = *(const float4*)(src + c8c * 8);
      const float4 u1 = *(const float4*)(src + c8c * 8 + 4);
      h8 hv = {(f16)u0.x, (f16)u0.y, (f16)u0.z, (f16)u0.w,
               (f16)u1.x, (f16)u1.y, (f16)u1.z, (f16)u1.w};
      *(h8*)(qf + ((size_t)(row0 >> 4) * 32 + c8c) * 128 + s_l * 8) = hv;
    }
    return;
  }

  __shared__ float tile[32][33];
  const int tx = tid & 31, ty = tid >> 5;
  const float* src;
  f16* dst;
  int S, tb, s_base = 0;

  if (t < 468) {
    const int tt0 = t - 128;
    const int b = (tt0 >= 170) ? 1 : 0;
    const int tt = tt0 - 170 * b;
    int soff;
    if (tt < 128)      { src = f0; S = 4096; soff = 0;    tb = tt; }
    else if (tt < 160) { src = f1; S = 1024; soff = 4096; tb = tt - 128; }
    else if (tt < 168) { src = f2; S = 256;  soff = 5120; tb = tt - 160; }
    else               { src = f3; S = 64;   soff = 5376; tb = tt - 168; }
    src += (size_t)b * 256 * S;
    dst = featT_f;
    s_base = b * S_TOT + soff;
  } else {
    const int tw = t - 468;
    if (tw < 8)       { src = W_off;  dst = Wcat_f; S = 256; tb = tw;      s_base = 0; }
    else if (tw < 12) { src = W_attn; dst = Wcat_f; S = 128; tb = tw - 8;  s_base = 256; }
    else if (tw < 20) { src = W_val;  dst = Wval_f; S = 256; tb = tw - 12; s_base = 0; }
    else              { src = W_out;  dst = Wout_f; S = 256; tb = tw - 20; s_base = 0; }
  }
  const int s0 = tb * 32, c0 = y * 32;

#pragma unroll
  for (int j = 0; j < 4; ++j) {
    const int c = c0 + ty + j * 8;
    tile[ty + j * 8][tx] = src[(size_t)c * S + s0 + tx];
  }
  __syncthreads();

  if (tid < 128) {
    const int s_l = tid >> 2, c8l = tid & 3;
    const int Sg = s_base + s0 + s_l;
    const int c8 = (c0 >> 3) + c8l;
    h8 v;
#pragma unroll
    for (int j = 0; j < 8; ++j) v[j] = (f16)tile[c8l * 8 + j][s_l];
    *(h8*)(dst + ((size_t)(Sg >> 4) * 32 + c8) * 128 + (Sg & 15) * 8) = v;
  }
}

// ---------------------------------------------------------------------------
// Fused GEMM (zero LDS/barriers, frag-linear) + bucket histogram.
// [0,340) vals; [340,852) offb/attnb; [852,916) histogram of refp buckets.
// ---------------------------------------------------------------------------
__global__ __launch_bounds__(256) void gemm_fused_kernel(
    const f16* __restrict__ qf, const f16* __restrict__ featT_f,
    const f16* __restrict__ Wcat_f, const f16* __restrict__ Wval_f,
    const float* __restrict__ b_val, const float* __restrict__ b_off,
    const float* __restrict__ b_attn, const float* __restrict__ refp,
    f16* __restrict__ vals, f16* __restrict__ offb, f16* __restrict__ attnb,
    int* __restrict__ hist) {
  const int t = blockIdx.x;
  const int tid = threadIdx.x;
  const int lane = tid & 63, wid = tid >> 6;
  const int l15 = lane & 15, l4 = lane >> 4;

  if (t >= 852) {  // histogram
    const int q = (t - 852) * 256 + tid;
    atomicAdd(&hist[bucket_of(refp, q)], 1);
    return;
  }

  if (t < 340) {
    const int g0 = t * 2;
    f32x4 acc[2][4] = {};
#pragma unroll
    for (int ks = 0; ks < 8; ++ks) {
      const int s2 = ks * 4 + l4;
      h8 a[2], b[4];
#pragma unroll
      for (int m = 0; m < 2; ++m)
        a[m] = *(const h8*)(featT_f + ((size_t)(g0 + m) * 32 + s2) * 128 + l15 * 8);
#pragma unroll
      for (int n = 0; n < 4; ++n)
        b[n] = *(const h8*)(Wval_f + ((size_t)(wid * 4 + n) * 32 + s2) * 128 + l15 * 8);
#pragma unroll
      for (int m = 0; m < 2; ++m)
#pragma unroll
        for (int n = 0; n < 4; ++n)
          acc[m][n] = __builtin_amdgcn_mfma_f32_16x16x32_f16(a[m], b[n], acc[m][n], 0, 0, 0);
    }
#pragma unroll
    for (int m = 0; m < 2; ++m)
#pragma unroll
      for (int n = 0; n < 4; ++n)
#pragma unroll
        for (int r = 0; r < 4; ++r) {
          const size_t rw = (size_t)t * 32 + m * 16 + l4 * 4 + r;
          const int col = wid * 64 + n * 16 + l15;
          vals[rw * 256 + col] = (f16)(acc[m][n][r] + b_val[col]);
        }
  } else {
    const int t2 = t - 340;
    const int g0 = t2 * 2;
    f32x4 acc[2][6] = {};
#pragma unroll
    for (int ks = 0; ks < 8; ++ks) {
      const int s2 = ks * 4 + l4;
      h8 a[2], b[6];
#pragma unroll
      for (int m = 0; m < 2; ++m)
        a[m] = *(const h8*)(qf + ((size_t)(g0 + m) * 32 + s2) * 128 + l15 * 8);
#pragma unroll
      for (int n = 0; n < 6; ++n)
        b[n] = *(const h8*)(Wcat_f + ((size_t)(wid * 6 + n) * 32 + s2) * 128 + l15 * 8);
#pragma unroll
      for (int m = 0; m < 2; ++m)
#pragma unroll
        for (int n = 0; n < 6; ++n)
          acc[m][n] = __builtin_amdgcn_mfma_f32_16x16x32_f16(a[m], b[n], acc[m][n], 0, 0, 0);
    }
#pragma unroll
    for (int m = 0; m < 2; ++m)
#pragma unroll
      for (int n = 0; n < 6; ++n)
#pragma unroll
        for (int r = 0; r < 4; ++r) {
          const size_t rw = (size_t)t2 * 32 + m * 16 + l4 * 4 + r;
          const int col = wid * 96 + n * 16 + l15;
          const float v = acc[m][n][r];
          if (col < 256)
            offb[rw * 256 + col] = (f16)(v + b_off[col]);
          else
            attnb[rw * 128 + (col - 256)] = (f16)(v + b_attn[col - 256]);
        }
  }
}

// ---------------------------------------------------------------------------
// sort: each of 64 blocks redundantly scans hist[512] in LDS (deterministic),
// then scatters its 256 queries: perm[base[bk] + atomic-rank] = q.
// perm CONTENT order within a bucket is nondeterministic, but every query's
// computation and output location are fixed -> final output deterministic.
// ---------------------------------------------------------------------------
__global__ __launch_bounds__(256) void sort_kernel(
    const float* __restrict__ refp, const int* __restrict__ hist,
    int* __restrict__ cnt, int* __restrict__ perm) {
  __shared__ int sc[512];
  const int tid = threadIdx.x;
  sc[tid] = hist[tid];
  sc[tid + 256] = hist[tid + 256];
  __syncthreads();
  for (int off = 1; off < 512; off <<= 1) {
    const int t0 = (tid >= off) ? sc[tid - off] : 0;
    const int t1 = (tid + 256 >= off) ? sc[tid + 256 - off] : 0;
    __syncthreads();
    sc[tid] += t0;
    sc[tid + 256] += t1;
    __syncthreads();
  }
  const int q = blockIdx.x * 256 + tid;
  const int bk = bucket_of(refp, q);
  const int base = bk ? sc[bk - 1] : 0;
  const int r = atomicAdd(&cnt[bk], 1);
  perm[base + r] = q;
}

// ---------------------------------------------------------------------------
// Out projection, zero LDS / zero barriers: samp_f (frag) @ Wout_f (frag).
// ---------------------------------------------------------------------------
__global__ __launch_bounds__(256) void gemm_out_kernel(
    const f16* __restrict__ A, const f16* __restrict__ Bt,
    const float* __restrict__ bias, float* __restrict__ out) {
  const int tid = threadIdx.x;
  const int lane = tid & 63, wid = tid >> 6;
  const int l15 = lane & 15, l4 = lane >> 4;
  const int g0 = blockIdx.x * 2;

  f32x4 acc[2][4] = {};
#pragma unroll
  for (int ks = 0; ks < 8; ++ks) {
    const int s2 = ks * 4 + l4;
    h8 a[2], b[4];
#pragma unroll
    for (int m = 0; m < 2; ++m)
      a[m] = *(const h8*)(A + ((size_t)(g0 + m) * 32 + s2) * 128 + l15 * 8);
#pragma unroll
    for (int n = 0; n < 4; ++n)
      b[n] = *(const h8*)(Bt + ((size_t)(wid * 4 + n) * 32 + s2) * 128 + l15 * 8);
#pragma unroll
    for (int m = 0; m < 2; ++m)
#pragma unroll
      for (int n = 0; n < 4; ++n)
        acc[m][n] = __builtin_amdgcn_mfma_f32_16x16x32_f16(a[m], b[n], acc[m][n], 0, 0, 0);
  }

#pragma unroll
  for (int m = 0; m < 2; ++m)
#pragma unroll
    for (int n = 0; n < 4; ++n)
#pragma unroll
      for (int r = 0; r < 4; ++r) {
        const size_t rw = (size_t)blockIdx.x * 32 + m * 16 + l4 * 4 + r;
        const int col = wid * 64 + n * 16 + l15;
        out[rw * 256 + col] = acc[m][n][r] + bias[col];
      }
}

// ---------------------------------------------------------------------------
// Sampling — bucketed 8-queries-per-block, no cross-lane reduce.
// Thread (qi=tid>>5, h=(tid>>2)&7, c4=tid&3).
// Phase 1: each thread computes params for the 4 points of level c4 of
//          (query qi, head h): softmax weight (4-lane shfl over the quad) +
//          bilinear {packed h2 weights, byte offsets} -> LDS (32 KB).
// Phase 2: each thread owns channels c4*8..+8 of (qi,h) and accumulates ALL
//          16 points x 4 corners (64 x 16B gathers, 4 chunks of 16, pk_fma).
//          Same-bucket queries share cache lines -> L1 reuse.
// ---------------------------------------------------------------------------
__global__ __launch_bounds__(256) void sample_kernel(
    const f16* __restrict__ vals, const f16* __restrict__ offb,
    const f16* __restrict__ attnb, const float* __restrict__ refp,
    const int* __restrict__ perm, f16* __restrict__ samp_f) {
  const int tid = threadIdx.x;
  const int qi = tid >> 5, hh = (tid >> 2) & 7, c4 = tid & 3;

  __shared__ int4 wts2[8][8][16];
  __shared__ int4 idxs[8][8][16];
  __shared__ int qbq[8];

  if (tid < 8) qbq[tid] = perm[blockIdx.x * 8 + tid];
  __syncthreads();

  const int bq = qbq[qi];
  const int b = bq >> 13;

  // ---- phase 1: 4 points (level l = c4) of (qi, hh) ----
  {
    const float rx = refp[(size_t)bq * 2 + 0];
    const float ry = refp[(size_t)bq * 2 + 1];
    const int pt0 = c4 * 4;

    const h4 lg = *(const h4*)(attnb + (size_t)bq * 128 + hh * 16 + pt0);
    float logit[4], e[4];
    float m = -1e30f;
#pragma unroll
    for (int p = 0; p < 4; ++p) { logit[p] = (float)lg[p]; m = fmaxf(m, logit[p]); }
    m = fmaxf(m, __shfl_xor(m, 1));
    m = fmaxf(m, __shfl_xor(m, 2));
    float s = 0.f;
#pragma unroll
    for (int p = 0; p < 4; ++p) { e[p] = __expf(logit[p] - m); s += e[p]; }
    s += __shfl_xor(s, 1);
    s += __shfl_xor(s, 2);
    const float inv = 1.0f / s;

    const h8 ov = *(const h8*)(offb + (size_t)bq * 256 + hh * 32 + pt0 * 2);
    const int l = c4;
    const int Wl = 64 >> l;
    const int loff = (l == 0) ? 0 : (l == 1) ? 4096 : (l == 2) ? 5120 : 5376;
    const int base = b * S_TOT + loff;

#pragma unroll
    for (int p = 0; p < 4; ++p) {
      const float aw = e[p] * inv;
      const float px = (rx + (float)ov[p * 2 + 0]) * (float)Wl - 0.5f;
      const float py = (ry + (float)ov[p * 2 + 1]) * (float)Wl - 0.5f;
      const float fx = floorf(px), fy = floorf(py);
      const float wx = px - fx, wy = py - fy;
      const int x0 = (int)fx, y0 = (int)fy;
      const int x1 = x0 + 1, y1 = y0 + 1;
      const float vx0 = (x0 >= 0 && x0 < Wl) ? 1.f : 0.f;
      const float vx1 = (x1 >= 0 && x1 < Wl) ? 1.f : 0.f;
      const float vy0 = (y0 >= 0 && y0 < Wl) ? 1.f : 0.f;
      const float vy1 = (y1 >= 0 && y1 < Wl) ? 1.f : 0.f;
      const int cx0 = min(max(x0, 0), Wl - 1), cx1 = min(max(x1, 0), Wl - 1);
      const int cy0 = min(max(y0, 0), Wl - 1), cy1 = min(max(y1, 0), Wl - 1);
      idxs[qi][hh][pt0 + p] = make_int4((base + cy0 * Wl + cx0) * 512,
                                        (base + cy0 * Wl + cx1) * 512,
                                        (base + cy1 * Wl + cx0) * 512,
                                        (base + cy1 * Wl + cx1) * 512);
      wts2[qi][hh][pt0 + p] = make_int4(pack_h2(aw * (1.f - wx) * (1.f - wy) * vx0 * vy0),
                                        pack_h2(aw * wx * (1.f - wy) * vx1 * vy0),
                                        pack_h2(aw * (1.f - wx) * wy * vx0 * vy1),
                                        pack_h2(aw * wx * wy * vx1 * vy1));
    }
  }
  __syncthreads();

  // ---- phase 2: all 16 pts x 4 corners for channels c4*8..+8 of (qi,hh) ----
  const char* vb = (const char*)vals + (hh * 64 + c4 * 16);
  h2 a2[4] = {};

#pragma unroll
  for (int ch = 0; ch < 4; ++ch) {
    int ids[16], wv[16];
#pragma unroll
    for (int p = 0; p < 4; ++p) {
      const int4 iv = idxs[qi][hh][ch * 4 + p];
      const int4 wv4 = wts2[qi][hh][ch * 4 + p];
      ids[p * 4 + 0] = iv.x; ids[p * 4 + 1] = iv.y;
      ids[p * 4 + 2] = iv.z; ids[p * 4 + 3] = iv.w;
      wv[p * 4 + 0] = wv4.x; wv[p * 4 + 1] = wv4.y;
      wv[p * 4 + 2] = wv4.z; wv[p * 4 + 3] = wv4.w;
    }
    h8 vv[16];
#pragma unroll
    for (int j = 0; j < 16; ++j) vv[j] = *(const h8*)(vb + ids[j]);
#pragma unroll
    for (int j = 0; j < 16; ++j) {
      union { int i; h2 h; } w; w.i = wv[j];
      const h2* vp = (const h2*)&vv[j];
      a2[0] += vp[0] * w.h;
      a2[1] += vp[1] * w.h;
      a2[2] += vp[2] * w.h;
      a2[3] += vp[3] * w.h;
    }
  }

  h8 r = {a2[0][0], a2[0][1], a2[1][0], a2[1][1],
          a2[2][0], a2[2][1], a2[3][0], a2[3][1]};
  *(h8*)(samp_f + ((size_t)(bq >> 4) * 32 + hh * 4 + c4) * 128 + (bq & 15) * 8) = r;
}

// ---------------------------------------------------------------------------
extern "C" void kernel_launch(void* const* d_in, const int* in_sizes, int n_in,
                              void* d_out, int out_size, void* d_ws, size_t ws_size,
                              hipStream_t stream) {
  const float* query = (const float*)d_in[0];
  const float* feat[4] = {(const float*)d_in[1], (const float*)d_in[2],
                          (const float*)d_in[3], (const float*)d_in[4]};
  const float* refp  = (const float*)d_in[5];
  const float* W_off = (const float*)d_in[6];
  const float* b_off = (const float*)d_in[7];
  const float* W_attn = (const float*)d_in[8];
  const float* b_attn = (const float*)d_in[9];
  const float* W_val = (const float*)d_in[10];
  const float* b_val = (const float*)d_in[11];
  const float* W_out = (const float*)d_in[12];
  const float* b_out = (const float*)d_in[13];
  float* out = (float*)d_out;

  // ---- workspace layout (f16 units; ~32.7 MB) ----
  f16* ws = (f16*)d_ws;
  f16* vals    = ws;                                  // [10880][256] linear 5.57MB
  f16* offb    = vals + (size_t)NB * S_TOT * 256;     // [16384][256] linear 8.4MB
  f16* attnb   = offb + (size_t)NB * QN * 256;        // [16384][128] linear 4.2MB
  f16* qf      = attnb + (size_t)NB * QN * 128;       // [16384][256] frag   8.4MB
  f16* samp_f  = qf;                                  // ALIAS: sample writes after
                                                      // gemm_fused consumed qf
  f16* featT_f = qf + (size_t)NB * QN * 256;          // [10880][256] frag   5.57MB
  f16* Wcat_f  = featT_f + (size_t)NB * S_TOT * 256;  // [384][256] frag
  f16* Wval_f  = Wcat_f + 384 * 256;                  // [256][256] frag
  f16* Wout_f  = Wval_f + 256 * 256;                  // [256][256] frag
  int* hist    = (int*)(Wout_f + 256 * 256);          // [512]
  int* cnt     = hist + 512;                          // [512]
  int* perm    = cnt + 512;                           // [16384]

  // 1. conversions/permutes + zero hist/cnt
  prep_kernel<<<dim3(497, 8), 256, 0, stream>>>(
      query, feat[0], feat[1], feat[2], feat[3],
      W_off, W_attn, W_val, W_out, qf, featT_f, Wcat_f, Wval_f, Wout_f,
      hist, cnt);

  // 2. value proj + offset/logit proj + bucket histogram
  gemm_fused_kernel<<<852 + 64, 256, 0, stream>>>(
      qf, featT_f, Wcat_f, Wval_f, b_val, b_off, b_attn, refp,
      vals, offb, attnb, hist);

  // 3. bucket scatter -> perm
  sort_kernel<<<64, 256, 0, stream>>>(refp, hist, cnt, perm);

  // 4. sampling, bucketed 8q/block -> samp_f (frag layout)
  sample_kernel<<<(NB * QN) / 8, 256, 0, stream>>>(
      vals, offb, attnb, refp, perm, samp_f);

  // 5. out projection -> d_out f32
  gemm_out_kernel<<<(NB * QN) / 32, 256, 0, stream>>>(samp_f, Wout_f, b_out, out);
}

// Round 15
// 73.988 us; speedup vs baseline: 1.0398x; 1.0398x over previous
//
#include <hip/hip_runtime.h>
#include <math.h>

#define NB 2
#define QN 8192
#define DIM 256
#define S_TOT 5440   // 4096+1024+256+64

typedef unsigned int uint32;
typedef _Float16 f16;
typedef __attribute__((ext_vector_type(8))) _Float16 h8;   // MFMA A/B frag (4 VGPR)
typedef __attribute__((ext_vector_type(2))) _Float16 h2;
typedef __attribute__((ext_vector_type(4))) float f32x4;   // MFMA C/D frag

__device__ __forceinline__ h2 shfl_h2(h2 v, int mask) {
  union { h2 h; int i; } u; u.h = v;
  u.i = __shfl_xor(u.i, mask);
  return u.h;
}
__device__ __forceinline__ int pack_h2(float w) {
  union { h2 h; int i; } u; const f16 wh = (f16)w; u.h = h2{wh, wh};
  return u.i;
}

// Fragment-linear layout: element (row s, col k) of a [S][256] f16 matrix lives
// at  ((s>>4)*32 + (k>>3))*128 + (s&15)*8 + (k&7).
// A wave's MFMA fragment load (16 rows x 8 k) is then base + lane*16B: coalesced.

// ---------------------------------------------------------------------------
// prep: query f32 -> qf (frag f16); feat -> featT_f (transpose+frag);
//       weights -> Wcat_f/Wval_f/Wout_f (transpose+frag). ONE launch.
// grid.x: [0,128) query (y = row-subtile), [128,468) feat tiles, [468,496) W.
// ---------------------------------------------------------------------------
__global__ __launch_bounds__(256) void prep_kernel(
    const float* __restrict__ q,
    const float* __restrict__ f0, const float* __restrict__ f1,
    const float* __restrict__ f2, const float* __restrict__ f3,
    const float* __restrict__ W_off, const float* __restrict__ W_attn,
    const float* __restrict__ W_val, const float* __restrict__ W_out,
    f16* __restrict__ qf, f16* __restrict__ featT_f,
    f16* __restrict__ Wcat_f, f16* __restrict__ Wval_f, f16* __restrict__ Wout_f) {
  const int t = blockIdx.x, y = blockIdx.y, tid = threadIdx.x;

  if (t < 128) {
    // ---- query: 16 rows x 256 cols per (t,y) ----
    const int row0 = (t * 8 + y) * 16;
    const int s_l = tid >> 4, c8 = tid & 15;
    const float* src = q + (size_t)(row0 + s_l) * 256;
#pragma unroll
    for (int cc = 0; cc < 2; ++cc) {
      const int c8c = c8 + cc * 16;
      const float4 u0 = *(const float4*)(src + c8c * 8);
      const float4 u1 = *(const float4*)(src + c8c * 8 + 4);
      h8 hv = {(f16)u0.x, (f16)u0.y, (f16)u0.z, (f16)u0.w,
               (f16)u1.x, (f16)u1.y, (f16)u1.z, (f16)u1.w};
      *(h8*)(qf + ((size_t)(row0 >> 4) * 32 + c8c) * 128 + s_l * 8) = hv;
    }
    return;
  }

  __shared__ float tile[32][33];
  const int tx = tid & 31, ty = tid >> 5;
  const float* src;
  f16* dst;
  int S, tb, s_base = 0;

  if (t < 468) {
    // ---- feat transpose tiles ----
    const int tt0 = t - 128;
    const int b = (tt0 >= 170) ? 1 : 0;
    const int tt = tt0 - 170 * b;
    int soff;
    if (tt < 128)      { src = f0; S = 4096; soff = 0;    tb = tt; }
    else if (tt < 160) { src = f1; S = 1024; soff = 4096; tb = tt - 128; }
    else if (tt < 168) { src = f2; S = 256;  soff = 5120; tb = tt - 160; }
    else               { src = f3; S = 64;   soff = 5376; tb = tt - 168; }
    src += (size_t)b * 256 * S;
    dst = featT_f;
    s_base = b * S_TOT + soff;
  } else {
    // ---- weight transpose tiles ----
    const int tw = t - 468;
    if (tw < 8)       { src = W_off;  dst = Wcat_f; S = 256; tb = tw;      s_base = 0; }
    else if (tw < 12) { src = W_attn; dst = Wcat_f; S = 128; tb = tw - 8;  s_base = 256; }
    else if (tw < 20) { src = W_val;  dst = Wval_f; S = 256; tb = tw - 12; s_base = 0; }
    else              { src = W_out;  dst = Wout_f; S = 256; tb = tw - 20; s_base = 0; }
  }
  const int s0 = tb * 32, c0 = y * 32;

#pragma unroll
  for (int j = 0; j < 4; ++j) {
    const int c = c0 + ty + j * 8;
    tile[ty + j * 8][tx] = src[(size_t)c * S + s0 + tx];
  }
  __syncthreads();

  if (tid < 128) {
    const int s_l = tid >> 2, c8l = tid & 3;
    const int Sg = s_base + s0 + s_l;
    const int c8 = (c0 >> 3) + c8l;
    h8 v;
#pragma unroll
    for (int j = 0; j < 8; ++j) v[j] = (f16)tile[c8l * 8 + j][s_l];
    *(h8*)(dst + ((size_t)(Sg >> 4) * 32 + c8) * 128 + (Sg & 15) * 8) = v;
  }
}

// ---------------------------------------------------------------------------
// Fused GEMM, zero LDS / zero barriers, frag-linear operands.
// blocks [0,340): vals[t*32..+32) = featT @ Wval + b_val (wave: 64 cols)
// blocks [340,852): offb/attnb = query @ Wcat + bias     (wave: 96 cols)
// ---------------------------------------------------------------------------
__global__ __launch_bounds__(256) void gemm_fused_kernel(
    const f16* __restrict__ qf, const f16* __restrict__ featT_f,
    const f16* __restrict__ Wcat_f, const f16* __restrict__ Wval_f,
    const float* __restrict__ b_val, const float* __restrict__ b_off,
    const float* __restrict__ b_attn,
    f16* __restrict__ vals, f16* __restrict__ offb, f16* __restrict__ attnb) {
  const int t = blockIdx.x;
  const int tid = threadIdx.x;
  const int lane = tid & 63, wid = tid >> 6;
  const int l15 = lane & 15, l4 = lane >> 4;

  if (t < 340) {
    const int g0 = t * 2;
    f32x4 acc[2][4] = {};
#pragma unroll
    for (int ks = 0; ks < 8; ++ks) {
      const int s2 = ks * 4 + l4;
      h8 a[2], b[4];
#pragma unroll
      for (int m = 0; m < 2; ++m)
        a[m] = *(const h8*)(featT_f + ((size_t)(g0 + m) * 32 + s2) * 128 + l15 * 8);
#pragma unroll
      for (int n = 0; n < 4; ++n)
        b[n] = *(const h8*)(Wval_f + ((size_t)(wid * 4 + n) * 32 + s2) * 128 + l15 * 8);
#pragma unroll
      for (int m = 0; m < 2; ++m)
#pragma unroll
        for (int n = 0; n < 4; ++n)
          acc[m][n] = __builtin_amdgcn_mfma_f32_16x16x32_f16(a[m], b[n], acc[m][n], 0, 0, 0);
    }
#pragma unroll
    for (int m = 0; m < 2; ++m)
#pragma unroll
      for (int n = 0; n < 4; ++n)
#pragma unroll
        for (int r = 0; r < 4; ++r) {
          const size_t rw = (size_t)t * 32 + m * 16 + l4 * 4 + r;
          const int col = wid * 64 + n * 16 + l15;
          vals[rw * 256 + col] = (f16)(acc[m][n][r] + b_val[col]);
        }
  } else {
    const int t2 = t - 340;
    const int g0 = t2 * 2;
    f32x4 acc[2][6] = {};
#pragma unroll
    for (int ks = 0; ks < 8; ++ks) {
      const int s2 = ks * 4 + l4;
      h8 a[2], b[6];
#pragma unroll
      for (int m = 0; m < 2; ++m)
        a[m] = *(const h8*)(qf + ((size_t)(g0 + m) * 32 + s2) * 128 + l15 * 8);
#pragma unroll
      for (int n = 0; n < 6; ++n)
        b[n] = *(const h8*)(Wcat_f + ((size_t)(wid * 6 + n) * 32 + s2) * 128 + l15 * 8);
#pragma unroll
      for (int m = 0; m < 2; ++m)
#pragma unroll
        for (int n = 0; n < 6; ++n)
          acc[m][n] = __builtin_amdgcn_mfma_f32_16x16x32_f16(a[m], b[n], acc[m][n], 0, 0, 0);
    }
#pragma unroll
    for (int m = 0; m < 2; ++m)
#pragma unroll
      for (int n = 0; n < 6; ++n)
#pragma unroll
        for (int r = 0; r < 4; ++r) {
          const size_t rw = (size_t)t2 * 32 + m * 16 + l4 * 4 + r;
          const int col = wid * 96 + n * 16 + l15;
          const float v = acc[m][n][r];
          if (col < 256)
            offb[rw * 256 + col] = (f16)(v + b_off[col]);
          else
            attnb[rw * 128 + (col - 256)] = (f16)(v + b_attn[col - 256]);
        }
  }
}

// ---------------------------------------------------------------------------
// FUSED sampling + out-projection. Block = 32 queries (512 blocks).
// 16 chunks of the R13-proven 2-query sample body; params double-buffered in
// LDS (one barrier per chunk); results to a padded frag-linear LDS buffer.
// Final phase: 32x256 @ 256x256 out-proj MFMA from LDS (B = L2-hot Wout_f),
// f32 store to d_out. No samp global round-trip, no separate launch.
// LDS samp layout: row = (rl>>4)*32 + c8  (rl = query-within-block),
// row stride 136 f16 (pad +8 -> stores 2-way, frag reads 2-way: both free).
// ---------------------------------------------------------------------------
__global__ __launch_bounds__(256) void sample_out_kernel(
    const f16* __restrict__ vals, const f16* __restrict__ offb,
    const f16* __restrict__ attnb, const float* __restrict__ refp,
    const f16* __restrict__ Wout_f, const float* __restrict__ b_out,
    float* __restrict__ out) {
  const int tid = threadIdx.x;
  const int g = tid & 15;
  const int grp = tid >> 4;
  const int h = grp & 7;
  const int half = tid >> 7;
  const int q0 = blockIdx.x * 32;

  __shared__ int4 wts2[2][16][17];   // double-buffered packed h2{w,w} weights
  __shared__ int4 idxs[2][16][17];   // double-buffered byte offsets
  __shared__ f16 samp[64 * 136];     // 17 KB, padded frag-linear

  const int c4 = g & 3, pc = g >> 2;
  const char* vb = (const char*)vals + (h * 64 + c4 * 16);

  for (int chunk = 0; chunk < 16; ++chunk) {
    const int buf = chunk & 1;
    const int bq = q0 + chunk * 2 + half;
    const int b = bq >> 13;

    // ---- phase 1: params for point g of (bq, h) ----
    {
      const float rx = refp[(size_t)bq * 2 + 0];
      const float ry = refp[(size_t)bq * 2 + 1];

      float logit = (float)attnb[(size_t)bq * 128 + h * 16 + g];
      float m = logit;
#pragma unroll
      for (int mask = 1; mask < 16; mask <<= 1)
        m = fmaxf(m, __shfl_xor(m, mask, 16));
      const float e = __expf(logit - m);
      float ssum = e;
#pragma unroll
      for (int mask = 1; mask < 16; mask <<= 1)
        ssum += __shfl_xor(ssum, mask, 16);
      const float aw = e / ssum;

      const h2 ov = *(const h2*)(offb + (size_t)bq * 256 + h * 32 + g * 2);
      const int l = g >> 2;
      const int Wl = 64 >> l;
      const int loff = (l == 0) ? 0 : (l == 1) ? 4096 : (l == 2) ? 5120 : 5376;

      const float px = (rx + (float)ov[0]) * (float)Wl - 0.5f;
      const float py = (ry + (float)ov[1]) * (float)Wl - 0.5f;
      const float fx = floorf(px), fy = floorf(py);
      const float wx = px - fx, wy = py - fy;
      const int x0 = (int)fx, y0 = (int)fy;
      const int x1 = x0 + 1, y1 = y0 + 1;
      const float vx0 = (x0 >= 0 && x0 < Wl) ? 1.f : 0.f;
      const float vx1 = (x1 >= 0 && x1 < Wl) ? 1.f : 0.f;
      const float vy0 = (y0 >= 0 && y0 < Wl) ? 1.f : 0.f;
      const float vy1 = (y1 >= 0 && y1 < Wl) ? 1.f : 0.f;
      const int cx0 = min(max(x0, 0), Wl - 1), cx1 = min(max(x1, 0), Wl - 1);
      const int cy0 = min(max(y0, 0), Wl - 1), cy1 = min(max(y1, 0), Wl - 1);
      const int base = b * S_TOT + loff;
      idxs[buf][grp][g] = make_int4((base + cy0 * Wl + cx0) * 512,
                                    (base + cy0 * Wl + cx1) * 512,
                                    (base + cy1 * Wl + cx0) * 512,
                                    (base + cy1 * Wl + cx1) * 512);
      wts2[buf][grp][g] = make_int4(pack_h2(aw * (1.f - wx) * (1.f - wy) * vx0 * vy0),
                                    pack_h2(aw * wx * (1.f - wy) * vx1 * vy0),
                                    pack_h2(aw * (1.f - wx) * wy * vx0 * vy1),
                                    pack_h2(aw * wx * wy * vx1 * vy1));
    }
    __syncthreads();  // params[buf] ready; also guards buf reuse (see R15 notes)

    // ---- phase 2: gathers + packed MAC ----
    int wv[16];
    int ids[16];
#pragma unroll
    for (int pt = 0; pt < 16; ++pt) {
      wv[pt] = ((const int*)&wts2[buf][grp][pt])[pc];
      ids[pt] = ((const int*)&idxs[buf][grp][pt])[pc];
    }
    h8 vv[16];
#pragma unroll
    for (int pt = 0; pt < 16; ++pt) vv[pt] = *(const h8*)(vb + ids[pt]);

    h2 a2[4] = {};
#pragma unroll
    for (int pt = 0; pt < 16; ++pt) {
      union { int i; h2 h; } w; w.i = wv[pt];
      const h2* vp = (const h2*)&vv[pt];
      a2[0] += vp[0] * w.h;
      a2[1] += vp[1] * w.h;
      a2[2] += vp[2] * w.h;
      a2[3] += vp[3] * w.h;
    }
#pragma unroll
    for (int j = 0; j < 4; ++j) {
      a2[j] += shfl_h2(a2[j], 4);
      a2[j] += shfl_h2(a2[j], 8);
    }
    if (pc == 0) {
      h8 r = {a2[0][0], a2[0][1], a2[1][0], a2[1][1],
              a2[2][0], a2[2][1], a2[3][0], a2[3][1]};
      const int rl = chunk * 2 + half;
      *(h8*)&samp[((rl >> 4) * 32 + h * 4 + c4) * 136 + (rl & 15) * 8] = r;
    }
  }
  __syncthreads();  // all samp rows of this block ready

  // ---- out projection: rows q0..q0+32 = samp(LDS) @ Wout_f + b_out ----
  const int lane = tid & 63, wid = tid >> 6;
  const int l15 = lane & 15, l4 = lane >> 4;

  f32x4 acc[2][4] = {};
#pragma unroll
  for (int ks = 0; ks < 8; ++ks) {
    const int s2 = ks * 4 + l4;
    h8 a[2], b[4];
#pragma unroll
    for (int m = 0; m < 2; ++m)
      a[m] = *(const h8*)&samp[(m * 32 + s2) * 136 + l15 * 8];
#pragma unroll
    for (int n = 0; n < 4; ++n)
      b[n] = *(const h8*)(Wout_f + ((size_t)(wid * 4 + n) * 32 + s2) * 128 + l15 * 8);
#pragma unroll
    for (int m = 0; m < 2; ++m)
#pragma unroll
      for (int n = 0; n < 4; ++n)
        acc[m][n] = __builtin_amdgcn_mfma_f32_16x16x32_f16(a[m], b[n], acc[m][n], 0, 0, 0);
  }

#pragma unroll
  for (int m = 0; m < 2; ++m)
#pragma unroll
    for (int n = 0; n < 4; ++n)
#pragma unroll
      for (int r = 0; r < 4; ++r) {
        const size_t rw = (size_t)q0 + m * 16 + l4 * 4 + r;
        const int col = wid * 64 + n * 16 + l15;
        out[rw * 256 + col] = acc[m][n][r] + b_out[col];
      }
}

// ---------------------------------------------------------------------------
extern "C" void kernel_launch(void* const* d_in, const int* in_sizes, int n_in,
                              void* d_out, int out_size, void* d_ws, size_t ws_size,
                              hipStream_t stream) {
  const float* query = (const float*)d_in[0];
  const float* feat[4] = {(const float*)d_in[1], (const float*)d_in[2],
                          (const float*)d_in[3], (const float*)d_in[4]};
  const float* refp  = (const float*)d_in[5];
  const float* W_off = (const float*)d_in[6];
  const float* b_off = (const float*)d_in[7];
  const float* W_attn = (const float*)d_in[8];
  const float* b_attn = (const float*)d_in[9];
  const float* W_val = (const float*)d_in[10];
  const float* b_val = (const float*)d_in[11];
  const float* W_out = (const float*)d_in[12];
  const float* b_out = (const float*)d_in[13];
  float* out = (float*)d_out;

  // ---- workspace layout (f16 units; ~32.6 MB) ----
  f16* ws = (f16*)d_ws;
  f16* vals    = ws;                                  // [10880][256] linear 5.57MB
  f16* offb    = vals + (size_t)NB * S_TOT * 256;     // [16384][256] linear 8.4MB
  f16* attnb   = offb + (size_t)NB * QN * 256;        // [16384][128] linear 4.2MB
  f16* qf      = attnb + (size_t)NB * QN * 128;       // [16384][256] frag   8.4MB
  f16* featT_f = qf + (size_t)NB * QN * 256;          // [10880][256] frag   5.57MB
  f16* Wcat_f  = featT_f + (size_t)NB * S_TOT * 256;  // [384][256] frag
  f16* Wval_f  = Wcat_f + 384 * 256;                  // [256][256] frag
  f16* Wout_f  = Wval_f + 256 * 256;                  // [256][256] frag

  // 1. all conversions/permutes in one launch
  prep_kernel<<<dim3(496, 8), 256, 0, stream>>>(
      query, feat[0], feat[1], feat[2], feat[3],
      W_off, W_attn, W_val, W_out, qf, featT_f, Wcat_f, Wval_f, Wout_f);

  // 2. value proj + offset/logit proj (zero-barrier streaming MFMA)
  gemm_fused_kernel<<<340 + 512, 256, 0, stream>>>(
      qf, featT_f, Wcat_f, Wval_f, b_val, b_off, b_attn, vals, offb, attnb);

  // 3. fused sampling + out projection -> d_out f32
  sample_out_kernel<<<(NB * QN) / 32, 256, 0, stream>>>(
      vals, offb, attnb, refp, Wout_f, b_out, out);
}

// Round 16
// 69.437 us; speedup vs baseline: 1.1080x; 1.0655x over previous
//
#include <hip/hip_runtime.h>
#include <math.h>

#define NB 2
#define QN 8192
#define DIM 256
#define S_TOT 5440   // 4096+1024+256+64

typedef unsigned int uint32;
typedef _Float16 f16;
typedef __attribute__((ext_vector_type(8))) _Float16 h8;   // MFMA A/B frag (4 VGPR)
typedef __attribute__((ext_vector_type(2))) _Float16 h2;
typedef __attribute__((ext_vector_type(4))) float f32x4;   // MFMA C/D frag

__device__ __forceinline__ h2 shfl_h2(h2 v, int mask) {
  union { h2 h; int i; } u; u.h = v;
  u.i = __shfl_xor(u.i, mask);
  return u.h;
}
__device__ __forceinline__ int pack_h2(float w) {
  union { h2 h; int i; } u; const f16 wh = (f16)w; u.h = h2{wh, wh};
  return u.i;
}

// Fragment-linear layout: element (row s, col k) of a [S][256] f16 matrix lives
// at  ((s>>4)*32 + (k>>3))*128 + (s&15)*8 + (k&7).
// A wave's MFMA fragment load (16 rows x 8 k) is then base + lane*16B: coalesced.

// ---------------------------------------------------------------------------
// prep: feat -> featT_f (transpose+frag); weights -> Wcat_f/Wval_f/Wout_f.
// (query pass ELIMINATED: qoff GEMM now converts f32 query in-register.)
// grid.x: [0,340) feat tiles, [340,368) weight tiles.
// ---------------------------------------------------------------------------
__global__ __launch_bounds__(256) void prep_kernel(
    const float* __restrict__ f0, const float* __restrict__ f1,
    const float* __restrict__ f2, const float* __restrict__ f3,
    const float* __restrict__ W_off, const float* __restrict__ W_attn,
    const float* __restrict__ W_val, const float* __restrict__ W_out,
    f16* __restrict__ featT_f,
    f16* __restrict__ Wcat_f, f16* __restrict__ Wval_f, f16* __restrict__ Wout_f) {
  const int t = blockIdx.x, y = blockIdx.y, tid = threadIdx.x;

  __shared__ float tile[32][33];
  const int tx = tid & 31, ty = tid >> 5;
  const float* src;
  f16* dst;
  int S, tb, s_base = 0;

  if (t < 340) {
    // ---- feat transpose tiles ----
    const int b = (t >= 170) ? 1 : 0;
    const int tt = t - 170 * b;
    int soff;
    if (tt < 128)      { src = f0; S = 4096; soff = 0;    tb = tt; }
    else if (tt < 160) { src = f1; S = 1024; soff = 4096; tb = tt - 128; }
    else if (tt < 168) { src = f2; S = 256;  soff = 5120; tb = tt - 160; }
    else               { src = f3; S = 64;   soff = 5376; tb = tt - 168; }
    src += (size_t)b * 256 * S;
    dst = featT_f;
    s_base = b * S_TOT + soff;
  } else {
    // ---- weight transpose tiles ----
    const int tw = t - 340;
    if (tw < 8)       { src = W_off;  dst = Wcat_f; S = 256; tb = tw;      s_base = 0; }
    else if (tw < 12) { src = W_attn; dst = Wcat_f; S = 128; tb = tw - 8;  s_base = 256; }
    else if (tw < 20) { src = W_val;  dst = Wval_f; S = 256; tb = tw - 12; s_base = 0; }
    else              { src = W_out;  dst = Wout_f; S = 256; tb = tw - 20; s_base = 0; }
  }
  const int s0 = tb * 32, c0 = y * 32;

#pragma unroll
  for (int j = 0; j < 4; ++j) {
    const int c = c0 + ty + j * 8;
    tile[ty + j * 8][tx] = src[(size_t)c * S + s0 + tx];
  }
  __syncthreads();

  if (tid < 128) {
    const int s_l = tid >> 2, c8l = tid & 3;
    const int Sg = s_base + s0 + s_l;
    const int c8 = (c0 >> 3) + c8l;
    h8 v;
#pragma unroll
    for (int j = 0; j < 8; ++j) v[j] = (f16)tile[c8l * 8 + j][s_l];
    *(h8*)(dst + ((size_t)(Sg >> 4) * 32 + c8) * 128 + (Sg & 15) * 8) = v;
  }
}

// ---------------------------------------------------------------------------
// Fused GEMM, zero LDS / zero barriers.
// blocks [0,340): vals[t*32..+32) = featT_f(frag) @ Wval_f + b_val
// blocks [340,852): offb/attnb = query(f32, cvt in regs) @ Wcat_f + bias
// B always frag-linear (coalesced). A for qoff: 16 rows x 128B contiguous
// per wave per (ks,m) — read once, streaming.
// ---------------------------------------------------------------------------
__global__ __launch_bounds__(256) void gemm_fused_kernel(
    const float* __restrict__ query, const f16* __restrict__ featT_f,
    const f16* __restrict__ Wcat_f, const f16* __restrict__ Wval_f,
    const float* __restrict__ b_val, const float* __restrict__ b_off,
    const float* __restrict__ b_attn,
    f16* __restrict__ vals, f16* __restrict__ offb, f16* __restrict__ attnb) {
  const int t = blockIdx.x;
  const int tid = threadIdx.x;
  const int lane = tid & 63, wid = tid >> 6;
  const int l15 = lane & 15, l4 = lane >> 4;

  if (t < 340) {
    const int g0 = t * 2;
    f32x4 acc[2][4] = {};
#pragma unroll
    for (int ks = 0; ks < 8; ++ks) {
      const int s2 = ks * 4 + l4;
      h8 a[2], b[4];
#pragma unroll
      for (int m = 0; m < 2; ++m)
        a[m] = *(const h8*)(featT_f + ((size_t)(g0 + m) * 32 + s2) * 128 + l15 * 8);
#pragma unroll
      for (int n = 0; n < 4; ++n)
        b[n] = *(const h8*)(Wval_f + ((size_t)(wid * 4 + n) * 32 + s2) * 128 + l15 * 8);
#pragma unroll
      for (int m = 0; m < 2; ++m)
#pragma unroll
        for (int n = 0; n < 4; ++n)
          acc[m][n] = __builtin_amdgcn_mfma_f32_16x16x32_f16(a[m], b[n], acc[m][n], 0, 0, 0);
    }
#pragma unroll
    for (int m = 0; m < 2; ++m)
#pragma unroll
      for (int n = 0; n < 4; ++n)
#pragma unroll
        for (int r = 0; r < 4; ++r) {
          const size_t rw = (size_t)t * 32 + m * 16 + l4 * 4 + r;
          const int col = wid * 64 + n * 16 + l15;
          vals[rw * 256 + col] = (f16)(acc[m][n][r] + b_val[col]);
        }
  } else {
    const int t2 = t - 340;
    const size_t r0 = (size_t)t2 * 32;
    f32x4 acc[2][6] = {};
#pragma unroll
    for (int ks = 0; ks < 8; ++ks) {
      const int s2 = ks * 4 + l4;
      const int k0 = s2 * 8;
      h8 a[2], b[6];
#pragma unroll
      for (int m = 0; m < 2; ++m) {
        const float* ga = query + (r0 + m * 16 + l15) * 256 + k0;
        const float4 u0 = *(const float4*)ga;
        const float4 u1 = *(const float4*)(ga + 4);
        h8 hv = {(f16)u0.x, (f16)u0.y, (f16)u0.z, (f16)u0.w,
                 (f16)u1.x, (f16)u1.y, (f16)u1.z, (f16)u1.w};
        a[m] = hv;
      }
#pragma unroll
      for (int n = 0; n < 6; ++n)
        b[n] = *(const h8*)(Wcat_f + ((size_t)(wid * 6 + n) * 32 + s2) * 128 + l15 * 8);
#pragma unroll
      for (int m = 0; m < 2; ++m)
#pragma unroll
        for (int n = 0; n < 6; ++n)
          acc[m][n] = __builtin_amdgcn_mfma_f32_16x16x32_f16(a[m], b[n], acc[m][n], 0, 0, 0);
    }
#pragma unroll
    for (int m = 0; m < 2; ++m)
#pragma unroll
      for (int n = 0; n < 6; ++n)
#pragma unroll
        for (int r = 0; r < 4; ++r) {
          const size_t rw = r0 + m * 16 + l4 * 4 + r;
          const int col = wid * 96 + n * 16 + l15;
          const float v = acc[m][n][r];
          if (col < 256)
            offb[rw * 256 + col] = (f16)(v + b_off[col]);
          else
            attnb[rw * 128 + (col - 256)] = (f16)(v + b_attn[col - 256]);
        }
  }
}

// ---------------------------------------------------------------------------
// Out projection, zero LDS / zero barriers: samp_f (frag) @ Wout_f (frag).
// 512 blocks x 32 rows; wave wid owns 64 cols.
// ---------------------------------------------------------------------------
__global__ __launch_bounds__(256) void gemm_out_kernel(
    const f16* __restrict__ A, const f16* __restrict__ Bt,
    const float* __restrict__ bias, float* __restrict__ out) {
  const int tid = threadIdx.x;
  const int lane = tid & 63, wid = tid >> 6;
  const int l15 = lane & 15, l4 = lane >> 4;
  const int g0 = blockIdx.x * 2;

  f32x4 acc[2][4] = {};
#pragma unroll
  for (int ks = 0; ks < 8; ++ks) {
    const int s2 = ks * 4 + l4;
    h8 a[2], b[4];
#pragma unroll
    for (int m = 0; m < 2; ++m)
      a[m] = *(const h8*)(A + ((size_t)(g0 + m) * 32 + s2) * 128 + l15 * 8);
#pragma unroll
    for (int n = 0; n < 4; ++n)
      b[n] = *(const h8*)(Bt + ((size_t)(wid * 4 + n) * 32 + s2) * 128 + l15 * 8);
#pragma unroll
    for (int m = 0; m < 2; ++m)
#pragma unroll
      for (int n = 0; n < 4; ++n)
        acc[m][n] = __builtin_amdgcn_mfma_f32_16x16x32_f16(a[m], b[n], acc[m][n], 0, 0, 0);
  }

#pragma unroll
  for (int m = 0; m < 2; ++m)
#pragma unroll
    for (int n = 0; n < 4; ++n)
#pragma unroll
      for (int r = 0; r < 4; ++r) {
        const size_t rw = (size_t)blockIdx.x * 32 + m * 16 + l4 * 4 + r;
        const int col = wid * 64 + n * 16 + l15;
        out[rw * 256 + col] = acc[m][n][r] + bias[col];
      }
}

// ---------------------------------------------------------------------------
// Sampling + softmax + weighted sum — packed-f16 MAC, NO BARRIER.
// Block = 2 queries; per query 8 heads x 16 lanes (grp).
// The param exchange (wts2/idxs[grp][*]) is strictly within one wave
// (grp = tid>>4; wave = grps 4w..4w+3, phase 2 reads only its own grp)
// -> no __syncthreads needed: per-wave LDS ops are in program order and
// the compiler orders the dependent reads via lgkmcnt. Waves run decoupled.
// Phase 2: 16 gathers back-to-back (MLP=16), v_pk_fma_f16 MAC, packed
// shfl reduce, frag-linear h8 store.
// ---------------------------------------------------------------------------
__global__ __launch_bounds__(256) void sample_kernel(
    const f16* __restrict__ vals, const f16* __restrict__ offb,
    const f16* __restrict__ attnb, const float* __restrict__ refp,
    f16* __restrict__ samp_f) {
  const int tid = threadIdx.x;
  const int g = tid & 15;
  const int grp = tid >> 4;
  const int h = grp & 7;
  const int half = tid >> 7;
  const int bq = blockIdx.x * 2 + half;
  const int b = bq >> 13;

  __shared__ int4 wts2[16][17];   // packed h2{w,w} per corner (wave-private rows)
  __shared__ int4 idxs[16][17];   // byte offsets per corner

  // ---- phase 1 ----
  const float rx = refp[(size_t)bq * 2 + 0];
  const float ry = refp[(size_t)bq * 2 + 1];

  float logit = (float)attnb[(size_t)bq * 128 + h * 16 + g];
  float m = logit;
#pragma unroll
  for (int mask = 1; mask < 16; mask <<= 1)
    m = fmaxf(m, __shfl_xor(m, mask, 16));
  const float e = __expf(logit - m);
  float ssum = e;
#pragma unroll
  for (int mask = 1; mask < 16; mask <<= 1)
    ssum += __shfl_xor(ssum, mask, 16);
  const float aw = e / ssum;

  const h2 ov = *(const h2*)(offb + (size_t)bq * 256 + h * 32 + g * 2);
  const int l = g >> 2;
  const int Wl = 64 >> l;
  const int loff = (l == 0) ? 0 : (l == 1) ? 4096 : (l == 2) ? 5120 : 5376;

  const float px = (rx + (float)ov[0]) * (float)Wl - 0.5f;
  const float py = (ry + (float)ov[1]) * (float)Wl - 0.5f;
  const float fx = floorf(px), fy = floorf(py);
  const float wx = px - fx, wy = py - fy;
  const int x0 = (int)fx, y0 = (int)fy;
  const int x1 = x0 + 1, y1 = y0 + 1;
  const float vx0 = (x0 >= 0 && x0 < Wl) ? 1.f : 0.f;
  const float vx1 = (x1 >= 0 && x1 < Wl) ? 1.f : 0.f;
  const float vy0 = (y0 >= 0 && y0 < Wl) ? 1.f : 0.f;
  const float vy1 = (y1 >= 0 && y1 < Wl) ? 1.f : 0.f;
  const int cx0 = min(max(x0, 0), Wl - 1), cx1 = min(max(x1, 0), Wl - 1);
  const int cy0 = min(max(y0, 0), Wl - 1), cy1 = min(max(y1, 0), Wl - 1);
  const int base = b * S_TOT + loff;
  idxs[grp][g] = make_int4((base + cy0 * Wl + cx0) * 512,
                           (base + cy0 * Wl + cx1) * 512,
                           (base + cy1 * Wl + cx0) * 512,
                           (base + cy1 * Wl + cx1) * 512);
  wts2[grp][g] = make_int4(pack_h2(aw * (1.f - wx) * (1.f - wy) * vx0 * vy0),
                           pack_h2(aw * wx * (1.f - wy) * vx1 * vy0),
                           pack_h2(aw * (1.f - wx) * wy * vx0 * vy1),
                           pack_h2(aw * wx * wy * vx1 * vy1));
  // NO __syncthreads: exchange is intra-wave (see kernel comment).

  // ---- phase 2 ----
  const int c4 = g & 3, pc = g >> 2;
  const char* vb = (const char*)vals + (h * 64 + c4 * 16);

  int wv[16];
  int ids[16];
#pragma unroll
  for (int pt = 0; pt < 16; ++pt) {
    wv[pt] = ((const int*)&wts2[grp][pt])[pc];
    ids[pt] = ((const int*)&idxs[grp][pt])[pc];
  }
  h8 vv[16];
#pragma unroll
  for (int pt = 0; pt < 16; ++pt) vv[pt] = *(const h8*)(vb + ids[pt]);

  h2 a2[4] = {};
#pragma unroll
  for (int pt = 0; pt < 16; ++pt) {
    union { int i; h2 h; } w; w.i = wv[pt];
    const h2* vp = (const h2*)&vv[pt];
    a2[0] += vp[0] * w.h;
    a2[1] += vp[1] * w.h;
    a2[2] += vp[2] * w.h;
    a2[3] += vp[3] * w.h;
  }
#pragma unroll
  for (int j = 0; j < 4; ++j) {
    a2[j] += shfl_h2(a2[j], 4);
    a2[j] += shfl_h2(a2[j], 8);
  }
  if (pc == 0) {
    h8 r = {a2[0][0], a2[0][1], a2[1][0], a2[1][1],
            a2[2][0], a2[2][1], a2[3][0], a2[3][1]};
    // frag-linear store: row bq, cols [h*32+c4*8 .. +8)
    *(h8*)(samp_f + ((size_t)(bq >> 4) * 32 + h * 4 + c4) * 128 + (bq & 15) * 8) = r;
  }
}

// ---------------------------------------------------------------------------
extern "C" void kernel_launch(void* const* d_in, const int* in_sizes, int n_in,
                              void* d_out, int out_size, void* d_ws, size_t ws_size,
                              hipStream_t stream) {
  const float* query = (const float*)d_in[0];
  const float* feat[4] = {(const float*)d_in[1], (const float*)d_in[2],
                          (const float*)d_in[3], (const float*)d_in[4]};
  const float* refp  = (const float*)d_in[5];
  const float* W_off = (const float*)d_in[6];
  const float* b_off = (const float*)d_in[7];
  const float* W_attn = (const float*)d_in[8];
  const float* b_attn = (const float*)d_in[9];
  const float* W_val = (const float*)d_in[10];
  const float* b_val = (const float*)d_in[11];
  const float* W_out = (const float*)d_in[12];
  const float* b_out = (const float*)d_in[13];
  float* out = (float*)d_out;

  // ---- workspace layout (f16 units; ~32.6 MB) ----
  f16* ws = (f16*)d_ws;
  f16* vals    = ws;                                  // [10880][256] linear 5.57MB
  f16* offb    = vals + (size_t)NB * S_TOT * 256;     // [16384][256] linear 8.4MB
  f16* attnb   = offb + (size_t)NB * QN * 256;        // [16384][128] linear 4.2MB
  f16* samp_f  = attnb + (size_t)NB * QN * 128;       // [16384][256] frag   8.4MB
  f16* featT_f = samp_f + (size_t)NB * QN * 256;      // [10880][256] frag   5.57MB
  f16* Wcat_f  = featT_f + (size_t)NB * S_TOT * 256;  // [384][256] frag
  f16* Wval_f  = Wcat_f + 384 * 256;                  // [256][256] frag
  f16* Wout_f  = Wval_f + 256 * 256;                  // [256][256] frag

  // 1. feat + weight transposes/permutes (query pass eliminated)
  prep_kernel<<<dim3(368, 8), 256, 0, stream>>>(
      feat[0], feat[1], feat[2], feat[3],
      W_off, W_attn, W_val, W_out, featT_f, Wcat_f, Wval_f, Wout_f);

  // 2. value proj + offset/logit proj (zero-barrier streaming MFMA,
  //    query converted in-register)
  gemm_fused_kernel<<<340 + 512, 256, 0, stream>>>(
      query, featT_f, Wcat_f, Wval_f, b_val, b_off, b_attn, vals, offb, attnb);

  // 3. sampling -> samp_f (frag layout), barrier-free
  sample_kernel<<<(NB * QN) / 2, 256, 0, stream>>>(vals, offb, attnb, refp, samp_f);

  // 4. out projection (zero-barrier streaming MFMA) -> d_out f32
  gemm_out_kernel<<<(NB * QN) / 32, 256, 0, stream>>>(samp_f, Wout_f, b_out, out);
}